// Round 1
// baseline (650.660 us; speedup 1.0000x reference)
//
#include <hip/hip_runtime.h>

#define BB 256
#define LL 196
#define RR 1024
#define AA 512
#define DD 2048

__device__ __forceinline__ float fast_tanh(float x) {
    // tanh(x) = 1 - 2/(exp(2x)+1); saturates correctly at +/-inf
    float e = __expf(2.0f * x);
    float r = __builtin_amdgcn_rcpf(e + 1.0f);
    return 1.0f - 2.0f * r;
}

// K1: att_h = h @ W_h + b_h   (M=256, K=1024, N=512)
// 32x32 output tiles, BK=32, 16x16 threads x (2x2 outputs each)
__global__ __launch_bounds__(256) void gemm_hWh(const float* __restrict__ h,
                                                const float* __restrict__ W,
                                                const float* __restrict__ bh,
                                                float* __restrict__ out) {
    __shared__ float As[32][33];
    __shared__ float Bs[32][33];
    const int bn = blockIdx.x;      // 0..15 (N/32)
    const int bm = blockIdx.y;      // 0..7  (M/32)
    const int t  = threadIdx.x;
    const int ty = t >> 4, tx = t & 15;
    const int lr = t >> 3;          // 0..31
    const int lc = (t & 7) * 4;     // 0,4,...,28

    float acc00 = 0.f, acc01 = 0.f, acc10 = 0.f, acc11 = 0.f;

    for (int k0 = 0; k0 < RR; k0 += 32) {
        float4 a4 = *(const float4*)&h[(size_t)(bm * 32 + lr) * RR + k0 + lc];
        float4 b4 = *(const float4*)&W[(size_t)(k0 + lr) * AA + bn * 32 + lc];
        As[lr][lc + 0] = a4.x; As[lr][lc + 1] = a4.y;
        As[lr][lc + 2] = a4.z; As[lr][lc + 3] = a4.w;
        Bs[lr][lc + 0] = b4.x; Bs[lr][lc + 1] = b4.y;
        Bs[lr][lc + 2] = b4.z; Bs[lr][lc + 3] = b4.w;
        __syncthreads();
#pragma unroll
        for (int kk = 0; kk < 32; ++kk) {
            float a0 = As[ty * 2 + 0][kk];
            float a1 = As[ty * 2 + 1][kk];
            float b0 = Bs[kk][tx * 2 + 0];
            float b1 = Bs[kk][tx * 2 + 1];
            acc00 += a0 * b0; acc01 += a0 * b1;
            acc10 += a1 * b0; acc11 += a1 * b1;
        }
        __syncthreads();
    }
    const int gm = bm * 32 + ty * 2;
    const int gn = bn * 32 + tx * 2;
    out[(size_t)(gm + 0) * AA + gn + 0] = acc00 + bh[gn + 0];
    out[(size_t)(gm + 0) * AA + gn + 1] = acc01 + bh[gn + 1];
    out[(size_t)(gm + 1) * AA + gn + 0] = acc10 + bh[gn + 0];
    out[(size_t)(gm + 1) * AA + gn + 1] = acc11 + bh[gn + 1];
}

// K2: dot[b,l] = sum_a tanh(f2[b,l,a] + att_h[b,a]) * w_a[a] + b_a
//     weight[b,l] = softmax_l(dot) * mask, renormalized
// one block per b; 4 waves; wave-per-row dot; block softmax.
__global__ __launch_bounds__(256) void attn_weights(
    const float* __restrict__ f2,      // [B,L,A]
    const float* __restrict__ masks,   // [B,L]
    const float* __restrict__ att_h,   // [B,A] (ws)
    const float* __restrict__ w_a,     // [A]
    const float* __restrict__ b_a,     // [1]
    float* __restrict__ weight)        // [B,L] (ws)
{
    __shared__ float ah[AA];
    __shared__ float wa[AA];
    __shared__ float dot[LL];
    __shared__ float red[256];

    const int b = blockIdx.x;
    const int t = threadIdx.x;

    for (int i = t; i < AA; i += 256) {
        ah[i] = att_h[(size_t)b * AA + i];
        wa[i] = w_a[i];
    }
    __syncthreads();

    const int wave = t >> 6, lane = t & 63;
    const float ba = b_a[0];
    const float* f2b = f2 + (size_t)b * LL * AA;

    for (int l = wave; l < LL; l += 4) {
        const float4* row = (const float4*)(f2b + (size_t)l * AA);
        const float4* ah4 = (const float4*)ah;
        const float4* wa4 = (const float4*)wa;
        float partial = 0.f;
#pragma unroll
        for (int j = 0; j < 2; ++j) {
            int idx = lane + 64 * j;            // float4 index, 0..127
            float4 v = row[idx];
            float4 av = ah4[idx];
            float4 wv = wa4[idx];
            partial += fast_tanh(v.x + av.x) * wv.x;
            partial += fast_tanh(v.y + av.y) * wv.y;
            partial += fast_tanh(v.z + av.z) * wv.z;
            partial += fast_tanh(v.w + av.w) * wv.w;
        }
#pragma unroll
        for (int off = 32; off; off >>= 1) partial += __shfl_down(partial, off);
        if (lane == 0) dot[l] = partial + ba;
    }
    __syncthreads();

    // block softmax over L with masked renormalization folded in:
    // weight_l = exp(dot_l - max)*mask_l / sum(exp(dot - max)*mask)
    float v = (t < LL) ? dot[t] : -1e30f;
    red[t] = v;
    __syncthreads();
#pragma unroll
    for (int s = 128; s; s >>= 1) {
        if (t < s) red[t] = fmaxf(red[t], red[t + s]);
        __syncthreads();
    }
    const float m = red[0];
    __syncthreads();
    float e = 0.f;
    if (t < LL) e = __expf(dot[t] - m) * masks[(size_t)b * LL + t];
    red[t] = e;
    __syncthreads();
#pragma unroll
    for (int s = 128; s; s >>= 1) {
        if (t < s) red[t] += red[t + s];
        __syncthreads();
    }
    const float inv = 1.0f / red[0];
    if (t < LL) weight[(size_t)b * LL + t] = e * inv;
}

// K3: att[b,d] = sum_l weight[b,l] * f1[b,l,d]
// grid (2 d-chunks, B), 256 threads x float4 (1024 floats per chunk)
__global__ __launch_bounds__(256) void weighted_sum(
    const float* __restrict__ f1,      // [B,L,D]
    const float* __restrict__ weight,  // [B,L] (ws)
    float* __restrict__ out)           // [B,D]
{
    __shared__ float w[LL];
    const int b = blockIdx.y;
    const int t = threadIdx.x;
    const int d0 = blockIdx.x * 1024 + t * 4;

    if (t < LL) w[t] = weight[(size_t)b * LL + t];
    __syncthreads();

    const float* base = f1 + (size_t)b * LL * DD + d0;
    float4 acc = {0.f, 0.f, 0.f, 0.f};
#pragma unroll 4
    for (int l = 0; l < LL; ++l) {
        float4 v = *(const float4*)(base + (size_t)l * DD);
        float wl = w[l];
        acc.x += wl * v.x; acc.y += wl * v.y;
        acc.z += wl * v.z; acc.w += wl * v.w;
    }
    *(float4*)&out[(size_t)b * DD + d0] = acc;
}

extern "C" void kernel_launch(void* const* d_in, const int* in_sizes, int n_in,
                              void* d_out, int out_size, void* d_ws, size_t ws_size,
                              hipStream_t stream) {
    const float* h   = (const float*)d_in[0];
    const float* f1  = (const float*)d_in[1];
    const float* f2  = (const float*)d_in[2];
    const float* msk = (const float*)d_in[3];
    const float* W   = (const float*)d_in[4];
    const float* bh  = (const float*)d_in[5];
    const float* wa  = (const float*)d_in[6];
    const float* ba  = (const float*)d_in[7];
    float* out = (float*)d_out;

    float* att_h  = (float*)d_ws;            // [B,A]  512 KB
    float* weight = att_h + (size_t)BB * AA; // [B,L]  200 KB

    gemm_hWh<<<dim3(16, 8), 256, 0, stream>>>(h, W, bh, att_h);
    attn_weights<<<BB, 256, 0, stream>>>(f2, msk, att_h, wa, ba, weight);
    weighted_sum<<<dim3(2, BB), 256, 0, stream>>>(f1, weight, out);
}

// Round 6
// 634.261 us; speedup vs baseline: 1.0259x; 1.0259x over previous
//
#include <hip/hip_runtime.h>

#define BB 256
#define LL 196
#define RR 1024
#define AA 512
#define DD 2048

__device__ __forceinline__ float fast_tanh(float x) {
    // tanh(x) = 1 - 2/(exp(2x)+1); saturates correctly at +/-inf
    float e = __expf(2.0f * x);
    return 1.0f - 2.0f * __builtin_amdgcn_rcpf(e + 1.0f);
}

// K1: att_h = h @ W_h + b_h   (M=256, K=1024, N=512)  -- ~6us, not the bottleneck
__global__ __launch_bounds__(256) void gemm_hWh(const float* __restrict__ h,
                                                const float* __restrict__ W,
                                                const float* __restrict__ bh,
                                                float* __restrict__ out) {
    __shared__ float As[32][33];
    __shared__ float Bs[32][33];
    const int bn = blockIdx.x;      // 0..15 (N/32)
    const int bm = blockIdx.y;      // 0..7  (M/32)
    const int t  = threadIdx.x;
    const int ty = t >> 4, tx = t & 15;
    const int lr = t >> 3;          // 0..31
    const int lc = (t & 7) * 4;     // 0,4,...,28

    float acc00 = 0.f, acc01 = 0.f, acc10 = 0.f, acc11 = 0.f;

    for (int k0 = 0; k0 < RR; k0 += 32) {
        float4 a4 = *(const float4*)&h[(size_t)(bm * 32 + lr) * RR + k0 + lc];
        float4 b4 = *(const float4*)&W[(size_t)(k0 + lr) * AA + bn * 32 + lc];
        As[lr][lc + 0] = a4.x; As[lr][lc + 1] = a4.y;
        As[lr][lc + 2] = a4.z; As[lr][lc + 3] = a4.w;
        Bs[lr][lc + 0] = b4.x; Bs[lr][lc + 1] = b4.y;
        Bs[lr][lc + 2] = b4.z; Bs[lr][lc + 3] = b4.w;
        __syncthreads();
#pragma unroll
        for (int kk = 0; kk < 32; ++kk) {
            float a0 = As[ty * 2 + 0][kk];
            float a1 = As[ty * 2 + 1][kk];
            float b0 = Bs[kk][tx * 2 + 0];
            float b1 = Bs[kk][tx * 2 + 1];
            acc00 += a0 * b0; acc01 += a0 * b1;
            acc10 += a1 * b0; acc11 += a1 * b1;
        }
        __syncthreads();
    }
    const int gm = bm * 32 + ty * 2;
    const int gn = bn * 32 + tx * 2;
    out[(size_t)(gm + 0) * AA + gn + 0] = acc00 + bh[gn + 0];
    out[(size_t)(gm + 0) * AA + gn + 1] = acc01 + bh[gn + 1];
    out[(size_t)(gm + 1) * AA + gn + 0] = acc10 + bh[gn + 0];
    out[(size_t)(gm + 1) * AA + gn + 1] = acc11 + bh[gn + 1];
}

// K2: fused  dot -> masked softmax -> weighted sum.  One block per b, 1024 thr.
// b_a is dropped: softmax is shift-invariant, so the scalar bias cancels exactly.
__global__ __launch_bounds__(1024) void attn_fused(
    const float* __restrict__ f1,      // [B,L,D]
    const float* __restrict__ f2,      // [B,L,A]
    const float* __restrict__ masks,   // [B,L]
    const float* __restrict__ att_h,   // [B,A] (ws)
    const float* __restrict__ w_a,     // [A]
    float* __restrict__ out)           // [B,D]
{
    __shared__ float dot[LL];
    __shared__ float red[256];
    __shared__ float w[LL];
    __shared__ float sacc[512 * 4];    // 8 KB combine buffer

    const int b = blockIdx.x;
    const int t = threadIdx.x;
    const int wave = t >> 6, lane = t & 63;

    // ---- phase 1: dot[l] = sum_a tanh(f2[b,l,a] + att_h[b,a]) * w_a[a] ----
    // each lane owns a = lane*8 .. lane*8+7, hoisted to registers
    const float4* ah4 = (const float4*)(att_h + (size_t)b * AA);
    const float4* wa4 = (const float4*)w_a;
    const float4 a0 = ah4[lane * 2], a1 = ah4[lane * 2 + 1];
    const float4 w0 = wa4[lane * 2], w1 = wa4[lane * 2 + 1];

    const float4* f2b = (const float4*)(f2 + (size_t)b * LL * AA);

    for (int l = wave; l < LL; l += 16) {
        float4 v0 = f2b[l * 128 + lane * 2];
        float4 v1 = f2b[l * 128 + lane * 2 + 1];
        float p = fast_tanh(v0.x + a0.x) * w0.x
                + fast_tanh(v0.y + a0.y) * w0.y
                + fast_tanh(v0.z + a0.z) * w0.z
                + fast_tanh(v0.w + a0.w) * w0.w
                + fast_tanh(v1.x + a1.x) * w1.x
                + fast_tanh(v1.y + a1.y) * w1.y
                + fast_tanh(v1.z + a1.z) * w1.z
                + fast_tanh(v1.w + a1.w) * w1.w;
#pragma unroll
        for (int off = 32; off; off >>= 1) p += __shfl_down(p, off);
        if (lane == 0) dot[l] = p;
    }
    __syncthreads();

    // ---- softmax over L with mask-renorm folded:  w_l = e_l*m_l / sum(e*m) ----
    if (t < 256) red[t] = (t < LL) ? dot[t] : -1e30f;
    __syncthreads();
#pragma unroll
    for (int s = 128; s; s >>= 1) {
        if (t < s) red[t] = fmaxf(red[t], red[t + s]);
        __syncthreads();
    }
    const float m = red[0];
    __syncthreads();
    float e = 0.f;
    if (t < LL) e = __expf(dot[t] - m) * masks[(size_t)b * LL + t];
    if (t < 256) red[t] = e;
    __syncthreads();
#pragma unroll
    for (int s = 128; s; s >>= 1) {
        if (t < s) red[t] += red[t + s];
        __syncthreads();
    }
    if (t < LL) w[t] = e * (1.0f / red[0]);
    __syncthreads();

    // ---- phase 2: out[b,d] = sum_l w[l] * f1[b,l,d] ----
    // threads 0..511 take l in [0,98), 512..1023 take l in [98,196); LDS combine.
    const int u    = t & 511;          // float4 column index, d = u*4
    const int half = t >> 9;
    const float4* f1b = (const float4*)(f1 + (size_t)b * LL * DD) + u;
    float4 acc = {0.f, 0.f, 0.f, 0.f};
    const int l0 = half * 98;
#pragma unroll 7
    for (int i = 0; i < 98; ++i) {
        const int l = l0 + i;
        float4 v = f1b[(size_t)l * 512];
        const float wl = w[l];
        acc.x += wl * v.x; acc.y += wl * v.y;
        acc.z += wl * v.z; acc.w += wl * v.w;
    }
    if (half == 1) *(float4*)&sacc[u * 4] = acc;
    __syncthreads();
    if (half == 0) {
        float4 o = *(float4*)&sacc[u * 4];
        acc.x += o.x; acc.y += o.y; acc.z += o.z; acc.w += o.w;
        *(float4*)&out[(size_t)b * DD + u * 4] = acc;
    }
}

extern "C" void kernel_launch(void* const* d_in, const int* in_sizes, int n_in,
                              void* d_out, int out_size, void* d_ws, size_t ws_size,
                              hipStream_t stream) {
    const float* h   = (const float*)d_in[0];
    const float* f1  = (const float*)d_in[1];
    const float* f2  = (const float*)d_in[2];
    const float* msk = (const float*)d_in[3];
    const float* W   = (const float*)d_in[4];
    const float* bh  = (const float*)d_in[5];
    const float* wa  = (const float*)d_in[6];
    // d_in[7] = b_a: unused — softmax is shift-invariant, the bias cancels.
    float* out = (float*)d_out;

    float* att_h = (float*)d_ws;     // [B,A] 512 KB

    gemm_hWh<<<dim3(16, 8), 256, 0, stream>>>(h, W, bh, att_h);
    attn_fused<<<BB, 1024, 0, stream>>>(f1, f2, msk, att_h, wa, out);
}

// Round 7
// 631.306 us; speedup vs baseline: 1.0307x; 1.0047x over previous
//
#include <hip/hip_runtime.h>

#define BB 256
#define LL 196
#define RR 1024
#define AA 512
#define DD 2048

__device__ __forceinline__ float fast_tanh(float x) {
    // tanh(x) = 1 - 2/(exp(2x)+1); saturates correctly at +/-inf
    float e = __expf(2.0f * x);
    return 1.0f - 2.0f * __builtin_amdgcn_rcpf(e + 1.0f);
}

// Fully fused: (h @ W_h + b_h) -> tanh-dot -> masked softmax -> weighted sum.
// One block per b, 1024 threads. No workspace, single launch.
// b_a dropped: softmax is shift-invariant, the scalar bias cancels exactly.
__global__ __launch_bounds__(1024) void attn_fused(
    const float* __restrict__ h,       // [B,R]
    const float* __restrict__ f1,      // [B,L,D]
    const float* __restrict__ f2,      // [B,L,A]
    const float* __restrict__ masks,   // [B,L]
    const float* __restrict__ W,       // [R,A]
    const float* __restrict__ bh,      // [A]
    const float* __restrict__ w_a,     // [A]
    float* __restrict__ out)           // [B,D]
{
    __shared__ float hs[RR];           // 4 KB  h-row
    __shared__ float ah[AA];           // 2 KB  att_h row
    __shared__ float dot[LL];
    __shared__ float red[256];
    __shared__ float w[LL];
    __shared__ float sacc[512 * 4];    // 8 KB combine buffer (stage B + phase 2)

    const int b = blockIdx.x;
    const int t = threadIdx.x;
    const int wave = t >> 6, lane = t & 63;

    // ---- stage A: h-row -> LDS ----
    if (t < 256) ((float4*)hs)[t] = ((const float4*)(h + (size_t)b * RR))[t];
    __syncthreads();

    // ---- stage B: ah[n] = sum_k hs[k]*W[k,n] + bh[n]  (k split in 2) ----
    {
        const int n  = t & 511;
        const int kh = t >> 9;                 // 0 or 1
        const float4* hs4 = (const float4*)hs;
        float acc = 0.f;
#pragma unroll 2
        for (int k4 = kh * 128; k4 < kh * 128 + 128; ++k4) {
            const float4 hv = hs4[k4];         // wave-uniform broadcast
            const float* Wk = W + (size_t)(k4 * 4) * AA + n;
            acc += hv.x * Wk[0 * AA];
            acc += hv.y * Wk[1 * AA];
            acc += hv.z * Wk[2 * AA];
            acc += hv.w * Wk[3 * AA];
        }
        if (kh == 1) sacc[n] = acc;
        __syncthreads();
        if (kh == 0) ah[n] = acc + sacc[n] + bh[n];
    }
    __syncthreads();

    // ---- phase 1: dot[l] = sum_a tanh(f2[b,l,a] + ah[a]) * w_a[a] ----
    // each lane owns a = lane*8 .. lane*8+7, hoisted to registers
    const float4* ah4 = (const float4*)ah;
    const float4* wa4 = (const float4*)w_a;
    const float4 a0 = ah4[lane * 2], a1 = ah4[lane * 2 + 1];
    const float4 w0 = wa4[lane * 2], w1 = wa4[lane * 2 + 1];

    const float4* f2b = (const float4*)(f2 + (size_t)b * LL * AA);

    for (int l = wave; l < LL; l += 16) {
        float4 v0 = f2b[l * 128 + lane * 2];
        float4 v1 = f2b[l * 128 + lane * 2 + 1];
        float p = fast_tanh(v0.x + a0.x) * w0.x
                + fast_tanh(v0.y + a0.y) * w0.y
                + fast_tanh(v0.z + a0.z) * w0.z
                + fast_tanh(v0.w + a0.w) * w0.w
                + fast_tanh(v1.x + a1.x) * w1.x
                + fast_tanh(v1.y + a1.y) * w1.y
                + fast_tanh(v1.z + a1.z) * w1.z
                + fast_tanh(v1.w + a1.w) * w1.w;
#pragma unroll
        for (int off = 32; off; off >>= 1) p += __shfl_down(p, off);
        if (lane == 0) dot[l] = p;
    }
    __syncthreads();

    // ---- softmax over L with mask-renorm folded:  w_l = e_l*m_l / sum(e*m) ----
    if (t < 256) red[t] = (t < LL) ? dot[t] : -1e30f;
    __syncthreads();
#pragma unroll
    for (int s = 128; s; s >>= 1) {
        if (t < s) red[t] = fmaxf(red[t], red[t + s]);
        __syncthreads();
    }
    const float m = red[0];
    __syncthreads();
    float e = 0.f;
    if (t < LL) e = __expf(dot[t] - m) * masks[(size_t)b * LL + t];
    if (t < 256) red[t] = e;
    __syncthreads();
#pragma unroll
    for (int s = 128; s; s >>= 1) {
        if (t < s) red[t] += red[t + s];
        __syncthreads();
    }
    if (t < LL) w[t] = e * (1.0f / red[0]);
    __syncthreads();

    // ---- phase 2: out[b,d] = sum_l w[l] * f1[b,l,d] ----
    // threads 0..511 take l in [0,98), 512..1023 take l in [98,196); LDS combine.
    const int u    = t & 511;          // float4 column index, d = u*4
    const int half = t >> 9;
    const float4* f1b = (const float4*)(f1 + (size_t)b * LL * DD) + u;
    float4 acc = {0.f, 0.f, 0.f, 0.f};
    const int l0 = half * 98;
#pragma unroll 7
    for (int i = 0; i < 98; ++i) {
        const int l = l0 + i;
        float4 v = f1b[(size_t)l * 512];
        const float wl = w[l];
        acc.x += wl * v.x; acc.y += wl * v.y;
        acc.z += wl * v.z; acc.w += wl * v.w;
    }
    if (half == 1) *(float4*)&sacc[u * 4] = acc;
    __syncthreads();
    if (half == 0) {
        float4 o = *(float4*)&sacc[u * 4];
        acc.x += o.x; acc.y += o.y; acc.z += o.z; acc.w += o.w;
        *(float4*)&out[(size_t)b * DD + u * 4] = acc;
    }
}

extern "C" void kernel_launch(void* const* d_in, const int* in_sizes, int n_in,
                              void* d_out, int out_size, void* d_ws, size_t ws_size,
                              hipStream_t stream) {
    const float* h   = (const float*)d_in[0];
    const float* f1  = (const float*)d_in[1];
    const float* f2  = (const float*)d_in[2];
    const float* msk = (const float*)d_in[3];
    const float* W   = (const float*)d_in[4];
    const float* bh  = (const float*)d_in[5];
    const float* wa  = (const float*)d_in[6];
    // d_in[7] = b_a: unused — softmax is shift-invariant, the bias cancels.
    float* out = (float*)d_out;

    attn_fused<<<BB, 1024, 0, stream>>>(h, f1, f2, msk, W, bh, wa, out);
}